// Round 3
// baseline (748.598 us; speedup 1.0000x reference)
//
#include <hip/hip_runtime.h>

#define EMBED 1024
#define SEQ   2048
#define BATCH 4
#define HEADS 16

typedef __attribute__((ext_vector_type(8))) short short8;   // 8 bf16 in 4 VGPRs
typedef __attribute__((ext_vector_type(4))) float floatx4;
typedef __attribute__((ext_vector_type(16))) float floatx16;

#define MFMA16(a, b, c) __builtin_amdgcn_mfma_f32_16x16x32_bf16((a), (b), (c), 0, 0, 0)
#define MFMA32(a, b, c) __builtin_amdgcn_mfma_f32_32x32x16_bf16((a), (b), (c), 0, 0, 0)
#define ATT_SCALE (0.125f * 1.44269504088896340736f)   // 1/sqrt(64) * log2(e), folded into Q

static __device__ __forceinline__ unsigned short f2bf(float f) {
  union { float f; unsigned int u; } v; v.f = f;
  unsigned int u = v.u;
  u += 0x7fffu + ((u >> 16) & 1u);       // RNE
  return (unsigned short)(u >> 16);
}

static __device__ __forceinline__ float bf2f_lo(unsigned u) {
  union { unsigned u; float f; } v; v.u = u << 16; return v.f;
}
static __device__ __forceinline__ float bf2f_hi(unsigned u) {
  union { unsigned u; float f; } v; v.u = u & 0xffff0000u; return v.f;
}

// v_cvt_pk_bf16_f32: dst.lo16 = bf16(lo), dst.hi16 = bf16(hi)  (RNE)
static __device__ __forceinline__ unsigned cvtpk(float lo, float hi) {
  unsigned r;
  asm("v_cvt_pk_bf16_f32 %0, %1, %2" : "=v"(r) : "v"(lo), "v"(hi));
  return r;
}

static __device__ __forceinline__ void async16(const unsigned short* g, unsigned short* l) {
  __builtin_amdgcn_global_load_lds(
      (const __attribute__((address_space(1))) void*)g,
      (__attribute__((address_space(3))) void*)l, 16, 0, 0);
}

// ---------------- fused prep: hidden fp32->bf16 (blocks 0..4095) +
//                  W[k][n]->WT[n][k] bf16 for Wq,Wk,Wv,Wp (blocks 4096..5119) ---
__global__ __launch_bounds__(256) void k_prep(const float* __restrict__ hid,
                                              unsigned short* __restrict__ hidA,
                                              const float* __restrict__ Wq, const float* __restrict__ Wk,
                                              const float* __restrict__ Wv, const float* __restrict__ Wp,
                                              unsigned short* __restrict__ WT) {
  __shared__ unsigned short tile[64][65];
  const int bid = blockIdx.x, tid = threadIdx.x;
  if (bid < 4096) {                       // cvt: 8 floats / thread
    int i = bid * 256 + tid;
    const float4* s = (const float4*)hid;
    float4 a = s[i * 2], b = s[i * 2 + 1];
    uint4 o;
    o.x = (unsigned)f2bf(a.x) | ((unsigned)f2bf(a.y) << 16);
    o.y = (unsigned)f2bf(a.z) | ((unsigned)f2bf(a.w) << 16);
    o.z = (unsigned)f2bf(b.x) | ((unsigned)f2bf(b.y) << 16);
    o.w = (unsigned)f2bf(b.z) | ((unsigned)f2bf(b.w) << 16);
    ((uint4*)hidA)[i] = o;
    return;
  }
  const int idx = bid - 4096;
  const int z = idx >> 8, rem = idx & 255;
  const float* src = (z == 0) ? Wq : (z == 1) ? Wk : (z == 2) ? Wv : Wp;
  unsigned short* dst = WT + (size_t)z * EMBED * EMBED;
  const int k0 = (rem & 15) * 64, n0 = (rem >> 4) * 64;
  for (int i = tid; i < 4096; i += 256) {
    int r = i >> 6, c = i & 63;
    tile[c][r] = f2bf(src[(size_t)(k0 + r) * EMBED + n0 + c]);
  }
  __syncthreads();
  for (int i = tid; i < 4096; i += 256) {
    int r = i >> 6, c = i & 63;
    dst[(size_t)(n0 + r) * EMBED + k0 + c] = tile[r][c];
  }
}

// ---------------- QKV GEMM: C[m][n] = A[m][k]*BT[n][k] + bias, bf16 out -------
// Q columns (n0<1024) pre-scaled by ATT_SCALE so attention needs no mul.
__global__ __launch_bounds__(256) void k_gemm_qkv(const unsigned short* __restrict__ A,
                                                  const unsigned short* __restrict__ BT,
                                                  const float* __restrict__ bq,
                                                  const float* __restrict__ bk,
                                                  const float* __restrict__ bv,
                                                  unsigned short* __restrict__ C) {
  __shared__ unsigned short Als[128 * 64];
  __shared__ unsigned short Bls[128 * 64];
  const int tid = threadIdx.x;
  const int m0 = blockIdx.x * 128, n0 = blockIdx.y * 128;
  const int w = tid >> 6, lane = tid & 63, l16 = lane & 15, quad = lane >> 4;
  const int l7 = l16 & 7;
  const int wrow = (w >> 1) * 64, wcol = (w & 1) * 64;

  floatx4 acc[4][4];
#pragma unroll
  for (int i = 0; i < 4; ++i)
#pragma unroll
    for (int j = 0; j < 4; ++j) acc[i][j] = {0.f, 0.f, 0.f, 0.f};

  const int srow = tid >> 3;
  const int scol = (((tid & 7) ^ (srow & 7)) * 8);
  const unsigned short* Ap = A + (size_t)(m0 + srow) * EMBED + scol;
  const unsigned short* Bp = BT + (size_t)(n0 + srow) * EMBED + scol;

  int ab[2], bb[2];
#pragma unroll
  for (int kc = 0; kc < 2; ++kc) {
    ab[kc] = (wrow + l16) * 64 + (((4 * kc + quad) ^ l7) << 3);
    bb[kc] = (wcol + l16) * 64 + (((4 * kc + quad) ^ l7) << 3);
  }

  for (int kt = 0; kt < 16; ++kt) {
    const int k0 = kt * 64;
#pragma unroll
    for (int i = 0; i < 4; ++i)
      async16(Ap + k0 + (size_t)i * 32 * EMBED, Als + i * 2048 + tid * 8);
#pragma unroll
    for (int i = 0; i < 4; ++i)
      async16(Bp + k0 + (size_t)i * 32 * EMBED, Bls + i * 2048 + tid * 8);
    __syncthreads();
    short8 af[4][2], bf[4][2];
#pragma unroll
    for (int mt = 0; mt < 4; ++mt)
#pragma unroll
      for (int kc = 0; kc < 2; ++kc)
        af[mt][kc] = *(const short8*)(Als + ab[kc] + mt * 1024);
#pragma unroll
    for (int nt = 0; nt < 4; ++nt)
#pragma unroll
      for (int kc = 0; kc < 2; ++kc)
        bf[nt][kc] = *(const short8*)(Bls + bb[kc] + nt * 1024);
#pragma unroll
    for (int kc = 0; kc < 2; ++kc)
#pragma unroll
      for (int mt = 0; mt < 4; ++mt)
#pragma unroll
        for (int nt = 0; nt < 4; ++nt)
          acc[mt][nt] = MFMA16(af[mt][kc], bf[nt][kc], acc[mt][nt]);
    __syncthreads();
  }

  const float* bsel = (n0 < 1024) ? bq : (n0 < 2048 ? bk : bv);
  const float scl = (n0 < 1024) ? ATT_SCALE : 1.0f;
  const int nb = n0 & 1023;
  float bias[4];
#pragma unroll
  for (int nt = 0; nt < 4; ++nt) bias[nt] = bsel[nb + wcol + nt * 16 + l16];
#pragma unroll
  for (int mt = 0; mt < 4; ++mt)
#pragma unroll
    for (int r = 0; r < 4; ++r) {
      int gm = m0 + wrow + mt * 16 + quad * 4 + r;
      size_t base = (size_t)gm * 3072 + n0 + wcol;
#pragma unroll
      for (int nt = 0; nt < 4; ++nt)
        C[base + nt * 16 + l16] = f2bf((acc[mt][nt][r] + bias[nt]) * scl);
    }
}

// ---------------- V[l][d] per (b,h) -> VT[b][h][d][l]  (plain transpose) ------
__global__ __launch_bounds__(256) void k_vt(const unsigned short* __restrict__ QKV,
                                            unsigned short* __restrict__ VT) {
  int lt = blockIdx.x;
  int bh = blockIdx.y;
  int b = bh >> 4, h = bh & 15;
  int l0 = lt * 64;
  __shared__ unsigned short tile[64][65];
  const unsigned short* src = QKV + (size_t)(b * SEQ) * 3072 + 2048 + h * 64;
  unsigned short* dst = VT + (size_t)bh * 64 * SEQ;
  int tid = threadIdx.x;
  for (int i = tid; i < 4096; i += 256) {
    int r = i >> 6, c = i & 63;
    tile[c][r] = src[(size_t)(l0 + r) * 3072 + c];
  }
  __syncthreads();
  for (int i = tid; i < 4096; i += 256) {
    int r = i >> 6, c = i & 63;                       // r: d, c: kv
    dst[(size_t)r * SEQ + l0 + c] = tile[r][c];
  }
}

// ---------------- attention v11: v10 + kv-split-2 (flash-decoding) ------------
// blockIdx.z = hv selects kv-half [hv*1024, hv*1024+1024).  Each block emits
// UNNORMALIZED partial O (bf16) + partial row-sums (fp32); k_comb merges.
// No max-subtraction is used anywhere, so partials combine by pure addition.
// 1024 blocks -> 4 blocks/CU (LDS 32KB x4 = 128KB), 4 waves/SIMD: 2x TLP.
__global__ __launch_bounds__(256, 4) void k_attn(const unsigned short* __restrict__ QKV,
                                                 const unsigned short* __restrict__ VT,
                                                 unsigned short* __restrict__ OP0,
                                                 unsigned short* __restrict__ OP1,
                                                 float* __restrict__ RSP) {
  const int bh = blockIdx.x, qt = blockIdx.y, hv = blockIdx.z;
  const int b = bh >> 4, h = bh & 15;
  const int tid = threadIdx.x;
  const int w = tid >> 6, lane = tid & 63;
  const int l32 = lane & 31, hi = lane >> 5;

  __shared__ unsigned short Kls[2][64 * 64];   // [buf][kv][d]  xor-chunk swizzled
  __shared__ unsigned short Vls[2][64 * 64];   // [buf][d][kv]  xor-chunk swizzled

  const unsigned short* Qb = QKV + (size_t)(b * SEQ + qt * 256 + w * 64) * 3072 + h * 64;
  const unsigned short* Kb = QKV + (size_t)(b * SEQ) * 3072 + 1024 + h * 64;
  const unsigned short* Vb = VT + (size_t)bh * 64 * SEQ;

  // Q fragments (B-operand of swapped QK): qf[qg][ds] holds
  // Q[q = qg*32 + l32][d = ds*16 + hi*8 + j]  (pre-scaled by ATT_SCALE)
  short8 qf[2][4];
#pragma unroll
  for (int qg = 0; qg < 2; ++qg)
#pragma unroll
    for (int ds = 0; ds < 4; ++ds)
      qf[qg][ds] = *(const short8*)(Qb + (size_t)(qg * 32 + l32) * 3072 + ds * 16 + hi * 8);

  floatx16 o[2][2];
  float rs[2] = {0.f, 0.f};
#pragma unroll
  for (int qg = 0; qg < 2; ++qg)
#pragma unroll
    for (int dg = 0; dg < 2; ++dg)
#pragma unroll
      for (int c = 0; c < 16; ++c) o[qg][dg][c] = 0.f;

  const int srow = tid >> 3;                              // 0..31
  const int scol = (((tid & 7) ^ (srow & 7)) * 8);        // swizzled source chunk
  const int kbase = hv * 16;                              // this block's kv-tiles

  // prologue: stage first tile into buf 0
  {
    const int kv0 = kbase * 64;
    async16(Kb + (size_t)(kv0 + srow) * 3072 + scol, Kls[0] + tid * 8);
    async16(Kb + (size_t)(kv0 + 32 + srow) * 3072 + scol, Kls[0] + 2048 + tid * 8);
    async16(Vb + (size_t)srow * SEQ + kv0 + scol, Vls[0] + tid * 8);
    async16(Vb + (size_t)(32 + srow) * SEQ + kv0 + scol, Vls[0] + 2048 + tid * 8);
  }
  __syncthreads();

  int cur = 0;
  for (int kt = 0; kt < 16; ++kt) {
    if (kt < 15) {                          // prefetch next tile into buf^1
      const int kn = (kbase + kt + 1) * 64;
      unsigned short* Kd = Kls[cur ^ 1];
      unsigned short* Vd = Vls[cur ^ 1];
      async16(Kb + (size_t)(kn + srow) * 3072 + scol, Kd + tid * 8);
      async16(Kb + (size_t)(kn + 32 + srow) * 3072 + scol, Kd + 2048 + tid * 8);
      async16(Vb + (size_t)srow * SEQ + kn + scol, Vd + tid * 8);
      async16(Vb + (size_t)(32 + srow) * SEQ + kn + scol, Vd + 2048 + tid * 8);
    }
    const unsigned short* Kc = Kls[cur];
    const unsigned short* Vc = Vls[cur];

    short8 pa[2][4];   // [qg][ks] packed P fragments (PV A-operand)
#pragma unroll
    for (int kvg = 0; kvg < 2; ++kvg) {
      short8 kf[4];    // K A-frags: lane = kv-row kvg*32+l32, k = d-chunk
#pragma unroll
      for (int ds = 0; ds < 4; ++ds) {
        const int row = kvg * 32 + l32;
        kf[ds] = *(const short8*)(Kc + row * 64 + (((ds * 2 + hi) ^ (row & 7)) << 3));
      }
#pragma unroll
      for (int qg = 0; qg < 2; ++qg) {
        floatx16 s;
#pragma unroll
        for (int c = 0; c < 16; ++c) s[c] = 0.f;
#pragma unroll
        for (int ds = 0; ds < 4; ++ds) s = MFMA32(kf[ds], qf[qg][ds], s);
        float p[16];
#pragma unroll
        for (int c = 0; c < 16; ++c) p[c] = __builtin_amdgcn_exp2f(s[c]);
        rs[qg] += (((p[0] + p[1]) + (p[2] + p[3])) + ((p[4] + p[5]) + (p[6] + p[7])))
                + (((p[8] + p[9]) + (p[10] + p[11])) + ((p[12] + p[13]) + (p[14] + p[15])));
#pragma unroll
        for (int half = 0; half < 2; ++half) {   // ks = kvg*2 + half
          unsigned w0 = cvtpk(p[half * 8 + 0], p[half * 8 + 1]);
          unsigned w1 = cvtpk(p[half * 8 + 2], p[half * 8 + 3]);
          unsigned w2 = cvtpk(p[half * 8 + 4], p[half * 8 + 5]);
          unsigned w3 = cvtpk(p[half * 8 + 6], p[half * 8 + 7]);
          asm("v_permlane32_swap_b32 %0, %1" : "+v"(w0), "+v"(w2));
          asm("v_permlane32_swap_b32 %0, %1" : "+v"(w1), "+v"(w3));
          union { unsigned u[4]; short8 s8; } pk;
          pk.u[0] = w0; pk.u[1] = w1; pk.u[2] = w2; pk.u[3] = w3;
          pa[qg][kvg * 2 + half] = pk.s8;
        }
      }
    }

    // O += P V   (V B-frags: lane = d-col dg*32+l32, k = kv-chunk)
#pragma unroll
    for (int dg = 0; dg < 2; ++dg) {
      short8 vf[4];
#pragma unroll
      for (int ks = 0; ks < 4; ++ks) {
        const int row = dg * 32 + l32;
        vf[ks] = *(const short8*)(Vc + row * 64 + (((ks * 2 + hi) ^ (row & 7)) << 3));
      }
#pragma unroll
      for (int qg = 0; qg < 2; ++qg)
#pragma unroll
        for (int ks = 0; ks < 4; ++ks)
          o[qg][dg] = MFMA32(pa[qg][ks], vf[ks], o[qg][dg]);
    }

    // single barrier: drains the prefetch after compute hid its latency,
    // and protects buf[cur^1] before the next iteration overwrites it
    __syncthreads();
    cur ^= 1;
  }

  // partial row sums: lanes l and l+32 hold the same q
  rs[0] += __shfl_xor(rs[0], 32);
  rs[1] += __shfl_xor(rs[1], 32);
  if (lane < 32) {
    float* rp = RSP + ((size_t)(hv * 64 + bh)) * SEQ + qt * 256 + w * 64;
    rp[l32] = rs[0];
    rp[32 + l32] = rs[1];
  }

  // write UNNORMALIZED partial O (bf16); O rows: q = (j&3)+8*(j>>2)+4*hi (+32qg)
  unsigned short* Od = hv ? OP1 : OP0;
#pragma unroll
  for (int qg = 0; qg < 2; ++qg)
#pragma unroll
    for (int j = 0; j < 16; ++j) {
      const int rl = (j & 3) + 8 * (j >> 2) + 4 * hi;
      const int gq = b * SEQ + qt * 256 + w * 64 + qg * 32 + rl;
      const size_t base = (size_t)gq * EMBED + h * 64;
#pragma unroll
      for (int dg = 0; dg < 2; ++dg)
        Od[base + dg * 32 + l32] = f2bf(o[qg][dg][j]);
    }
}

// ---------------- combine: ctx = (O0 + O1) / (rs0 + rs1), bf16 ----------------
__global__ __launch_bounds__(256) void k_comb(const unsigned short* __restrict__ OP0,
                                              const unsigned short* __restrict__ OP1,
                                              const float* __restrict__ RSP,
                                              unsigned short* __restrict__ CTX) {
  const int gq = blockIdx.x, tid = threadIdx.x;
  const int b = gq >> 11, q = gq & 2047;
  const int col = tid * 4, h = col >> 6;
  const float inv = 1.f / (RSP[((size_t)(b * 16 + h)) * SEQ + q] +
                           RSP[((size_t)(64 + b * 16 + h)) * SEQ + q]);
  const size_t base = (size_t)gq * EMBED + col;
  uint2 ua = *(const uint2*)(OP0 + base);
  uint2 ub = *(const uint2*)(OP1 + base);
  float c0 = (bf2f_lo(ua.x) + bf2f_lo(ub.x)) * inv;
  float c1 = (bf2f_hi(ua.x) + bf2f_hi(ub.x)) * inv;
  float c2 = (bf2f_lo(ua.y) + bf2f_lo(ub.y)) * inv;
  float c3 = (bf2f_hi(ua.y) + bf2f_hi(ub.y)) * inv;
  uint2 oo;
  oo.x = (unsigned)f2bf(c0) | ((unsigned)f2bf(c1) << 16);
  oo.y = (unsigned)f2bf(c2) | ((unsigned)f2bf(c3) << 16);
  *(uint2*)(CTX + base) = oo;
}

// ---------------- proj GEMM + bias + residual -> fp32 x ----------------
__global__ __launch_bounds__(256) void k_gemm_proj(const unsigned short* __restrict__ A,
                                                   const unsigned short* __restrict__ BT,
                                                   const float* __restrict__ bp,
                                                   const float* __restrict__ hid,
                                                   float* __restrict__ X) {
  __shared__ unsigned short Als[128 * 64];
  __shared__ unsigned short Bls[128 * 64];
  const int tid = threadIdx.x;
  const int m0 = blockIdx.x * 128, n0 = blockIdx.y * 128;
  const int w = tid >> 6, lane = tid & 63, l16 = lane & 15, quad = lane >> 4;
  const int l7 = l16 & 7;
  const int wrow = (w >> 1) * 64, wcol = (w & 1) * 64;

  floatx4 acc[4][4];
#pragma unroll
  for (int i = 0; i < 4; ++i)
#pragma unroll
    for (int j = 0; j < 4; ++j) acc[i][j] = {0.f, 0.f, 0.f, 0.f};

  const int srow = tid >> 3;
  const int scol = (((tid & 7) ^ (srow & 7)) * 8);
  const unsigned short* Ap = A + (size_t)(m0 + srow) * EMBED + scol;
  const unsigned short* Bp = BT + (size_t)(n0 + srow) * EMBED + scol;

  int ab[2], bb[2];
#pragma unroll
  for (int kc = 0; kc < 2; ++kc) {
    ab[kc] = (wrow + l16) * 64 + (((4 * kc + quad) ^ l7) << 3);
    bb[kc] = (wcol + l16) * 64 + (((4 * kc + quad) ^ l7) << 3);
  }

  for (int kt = 0; kt < 16; ++kt) {
    const int k0 = kt * 64;
#pragma unroll
    for (int i = 0; i < 4; ++i)
      async16(Ap + k0 + (size_t)i * 32 * EMBED, Als + i * 2048 + tid * 8);
#pragma unroll
    for (int i = 0; i < 4; ++i)
      async16(Bp + k0 + (size_t)i * 32 * EMBED, Bls + i * 2048 + tid * 8);
    __syncthreads();
    short8 af[4][2], bf[4][2];
#pragma unroll
    for (int mt = 0; mt < 4; ++mt)
#pragma unroll
      for (int kc = 0; kc < 2; ++kc)
        af[mt][kc] = *(const short8*)(Als + ab[kc] + mt * 1024);
#pragma unroll
    for (int nt = 0; nt < 4; ++nt)
#pragma unroll
      for (int kc = 0; kc < 2; ++kc)
        bf[nt][kc] = *(const short8*)(Bls + bb[kc] + nt * 1024);
#pragma unroll
    for (int kc = 0; kc < 2; ++kc)
#pragma unroll
      for (int mt = 0; mt < 4; ++mt)
#pragma unroll
        for (int nt = 0; nt < 4; ++nt)
          acc[mt][nt] = MFMA16(af[mt][kc], bf[nt][kc], acc[mt][nt]);
    __syncthreads();
  }

  float bias[4];
#pragma unroll
  for (int nt = 0; nt < 4; ++nt) bias[nt] = bp[n0 + wcol + nt * 16 + l16];
#pragma unroll
  for (int mt = 0; mt < 4; ++mt)
#pragma unroll
    for (int r = 0; r < 4; ++r) {
      int gm = m0 + wrow + mt * 16 + quad * 4 + r;
      size_t base = (size_t)gm * EMBED + n0 + wcol;
#pragma unroll
      for (int nt = 0; nt < 4; ++nt) {
        size_t idx = base + nt * 16 + l16;
        X[idx] = acc[mt][nt][r] + bias[nt] + hid[idx];
      }
    }
}

// ---------------- in-place LayerNorm over E=1024, one block per row ----------------
__global__ __launch_bounds__(256) void k_ln(float* __restrict__ x,
                                            const float* __restrict__ gamma,
                                            const float* __restrict__ beta) {
  int row = blockIdx.x, tid = threadIdx.x;
  float4* rp = (float4*)(x + (size_t)row * EMBED);
  float4 v = rp[tid];
  float s = v.x + v.y + v.z + v.w;
  float q = v.x * v.x + v.y * v.y + v.z * v.z + v.w * v.w;
#pragma unroll
  for (int off = 1; off < 64; off <<= 1) {
    s += __shfl_xor(s, off);
    q += __shfl_xor(q, off);
  }
  __shared__ float ss[4], sq[4];
  int w = tid >> 6;
  if ((tid & 63) == 0) { ss[w] = s; sq[w] = q; }
  __syncthreads();
  s = ss[0] + ss[1] + ss[2] + ss[3];
  q = sq[0] + sq[1] + sq[2] + sq[3];
  float mean = s * (1.f / 1024.f);
  float var = q * (1.f / 1024.f) - mean * mean;
  float rstd = rsqrtf(var + 1e-8f);
  float4 g = ((const float4*)gamma)[tid];
  float4 be = ((const float4*)beta)[tid];
  v.x = (v.x - mean) * rstd * g.x + be.x;
  v.y = (v.y - mean) * rstd * g.y + be.y;
  v.z = (v.z - mean) * rstd * g.z + be.z;
  v.w = (v.w - mean) * rstd * g.w + be.w;
  rp[tid] = v;
}

extern "C" void kernel_launch(void* const* d_in, const int* in_sizes, int n_in,
                              void* d_out, int out_size, void* d_ws, size_t ws_size,
                              hipStream_t stream) {
  const float* hid   = (const float*)d_in[0];
  const float* Wq    = (const float*)d_in[1];
  const float* bq    = (const float*)d_in[2];
  const float* Wk    = (const float*)d_in[3];
  const float* bk    = (const float*)d_in[4];
  const float* Wv    = (const float*)d_in[5];
  const float* bv    = (const float*)d_in[6];
  const float* Wp    = (const float*)d_in[7];
  const float* bp    = (const float*)d_in[8];
  const float* gamma = (const float*)d_in[9];
  const float* beta  = (const float*)d_in[10];
  float* out = (float*)d_out;

  char* ws = (char*)d_ws;
  unsigned short* hidA = (unsigned short*)ws;                          // 16 MB  [8192][1024]
  unsigned short* WT   = (unsigned short*)(ws + (size_t)(16 << 20));   //  8 MB  [4096][1024]
  unsigned short* QKV  = (unsigned short*)(ws + (size_t)(24 << 20));   // 48 MB  [8192][3072]
  unsigned short* VT   = (unsigned short*)(ws + (size_t)(72 << 20));   // 16 MB  [64][64][2048]
  unsigned short* CTX  = (unsigned short*)(ws + (size_t)(88 << 20));   // 16 MB  [8192][1024]
  unsigned short* OP0  = (unsigned short*)ws;                          // 16 MB  overlays hidA (dead after qkv)
  unsigned short* OP1  = (unsigned short*)(ws + (size_t)(104 << 20));  // 16 MB
  float*          RSP  = (float*)(ws + (size_t)(120 << 20));           //  1 MB  [2][64][2048]

  k_prep<<<5120, 256, 0, stream>>>(hid, hidA, Wq, Wk, Wv, Wp, WT);
  k_gemm_qkv<<<dim3(64, 24), 256, 0, stream>>>(hidA, WT, bq, bk, bv, QKV);
  k_vt<<<dim3(32, 64), 256, 0, stream>>>(QKV, VT);
  k_attn<<<dim3(64, 8, 2), 256, 0, stream>>>(QKV, VT, OP0, OP1, RSP);
  k_comb<<<8192, 256, 0, stream>>>(OP0, OP1, RSP, CTX);
  k_gemm_proj<<<dim3(64, 8), 256, 0, stream>>>(CTX, WT + (size_t)3 * EMBED * EMBED, bp, hid, out);
  k_ln<<<8192, 256, 0, stream>>>(out, gamma, beta);
}

// Round 4
// 305.718 us; speedup vs baseline: 2.4487x; 2.4487x over previous
//
#include <hip/hip_runtime.h>

#define EMBED 1024
#define SEQ   2048
#define BATCH 4
#define HEADS 16

typedef __attribute__((ext_vector_type(8))) short short8;   // 8 bf16 in 4 VGPRs
typedef __attribute__((ext_vector_type(4))) float floatx4;
typedef __attribute__((ext_vector_type(16))) float floatx16;

#define MFMA16(a, b, c) __builtin_amdgcn_mfma_f32_16x16x32_bf16((a), (b), (c), 0, 0, 0)
#define MFMA32(a, b, c) __builtin_amdgcn_mfma_f32_32x32x16_bf16((a), (b), (c), 0, 0, 0)
#define ATT_SCALE (0.125f * 1.44269504088896340736f)   // 1/sqrt(64) * log2(e), folded into Q

static __device__ __forceinline__ unsigned short f2bf(float f) {
  union { float f; unsigned int u; } v; v.f = f;
  unsigned int u = v.u;
  u += 0x7fffu + ((u >> 16) & 1u);       // RNE
  return (unsigned short)(u >> 16);
}

// v_cvt_pk_bf16_f32: dst.lo16 = bf16(lo), dst.hi16 = bf16(hi)  (RNE)
static __device__ __forceinline__ unsigned cvtpk(float lo, float hi) {
  unsigned r;
  asm("v_cvt_pk_bf16_f32 %0, %1, %2" : "=v"(r) : "v"(lo), "v"(hi));
  return r;
}

static __device__ __forceinline__ void async16(const unsigned short* g, unsigned short* l) {
  __builtin_amdgcn_global_load_lds(
      (const __attribute__((address_space(1))) void*)g,
      (__attribute__((address_space(3))) void*)l, 16, 0, 0);
}

// ---------------- fused prep: hidden fp32->bf16 (blocks 0..4095) +
//                  W[k][n]->WT[n][k] bf16 for Wq,Wk,Wv,Wp (blocks 4096..5119) ---
__global__ __launch_bounds__(256) void k_prep(const float* __restrict__ hid,
                                              unsigned short* __restrict__ hidA,
                                              const float* __restrict__ Wq, const float* __restrict__ Wk,
                                              const float* __restrict__ Wv, const float* __restrict__ Wp,
                                              unsigned short* __restrict__ WT) {
  __shared__ unsigned short tile[64][65];
  const int bid = blockIdx.x, tid = threadIdx.x;
  if (bid < 4096) {                       // cvt: 8 floats / thread
    int i = bid * 256 + tid;
    const float4* s = (const float4*)hid;
    float4 a = s[i * 2], b = s[i * 2 + 1];
    uint4 o;
    o.x = (unsigned)f2bf(a.x) | ((unsigned)f2bf(a.y) << 16);
    o.y = (unsigned)f2bf(a.z) | ((unsigned)f2bf(a.w) << 16);
    o.z = (unsigned)f2bf(b.x) | ((unsigned)f2bf(b.y) << 16);
    o.w = (unsigned)f2bf(b.z) | ((unsigned)f2bf(b.w) << 16);
    ((uint4*)hidA)[i] = o;
    return;
  }
  const int idx = bid - 4096;
  const int z = idx >> 8, rem = idx & 255;
  const float* src = (z == 0) ? Wq : (z == 1) ? Wk : (z == 2) ? Wv : Wp;
  unsigned short* dst = WT + (size_t)z * EMBED * EMBED;
  const int k0 = (rem & 15) * 64, n0 = (rem >> 4) * 64;
  for (int i = tid; i < 4096; i += 256) {
    int r = i >> 6, c = i & 63;
    tile[c][r] = f2bf(src[(size_t)(k0 + r) * EMBED + n0 + c]);
  }
  __syncthreads();
  for (int i = tid; i < 4096; i += 256) {
    int r = i >> 6, c = i & 63;
    dst[(size_t)(n0 + r) * EMBED + k0 + c] = tile[r][c];
  }
}

// ---------------- QKV GEMM: C[m][n] = A[m][k]*BT[n][k] + bias, bf16 out -------
// Q columns (n0<1024) pre-scaled by ATT_SCALE so attention needs no mul.
__global__ __launch_bounds__(256) void k_gemm_qkv(const unsigned short* __restrict__ A,
                                                  const unsigned short* __restrict__ BT,
                                                  const float* __restrict__ bq,
                                                  const float* __restrict__ bk,
                                                  const float* __restrict__ bv,
                                                  unsigned short* __restrict__ C) {
  __shared__ unsigned short Als[128 * 64];
  __shared__ unsigned short Bls[128 * 64];
  const int tid = threadIdx.x;
  const int m0 = blockIdx.x * 128, n0 = blockIdx.y * 128;
  const int w = tid >> 6, lane = tid & 63, l16 = lane & 15, quad = lane >> 4;
  const int l7 = l16 & 7;
  const int wrow = (w >> 1) * 64, wcol = (w & 1) * 64;

  floatx4 acc[4][4];
#pragma unroll
  for (int i = 0; i < 4; ++i)
#pragma unroll
    for (int j = 0; j < 4; ++j) acc[i][j] = {0.f, 0.f, 0.f, 0.f};

  const int srow = tid >> 3;
  const int scol = (((tid & 7) ^ (srow & 7)) * 8);
  const unsigned short* Ap = A + (size_t)(m0 + srow) * EMBED + scol;
  const unsigned short* Bp = BT + (size_t)(n0 + srow) * EMBED + scol;

  int ab[2], bb[2];
#pragma unroll
  for (int kc = 0; kc < 2; ++kc) {
    ab[kc] = (wrow + l16) * 64 + (((4 * kc + quad) ^ l7) << 3);
    bb[kc] = (wcol + l16) * 64 + (((4 * kc + quad) ^ l7) << 3);
  }

  for (int kt = 0; kt < 16; ++kt) {
    const int k0 = kt * 64;
#pragma unroll
    for (int i = 0; i < 4; ++i)
      async16(Ap + k0 + (size_t)i * 32 * EMBED, Als + i * 2048 + tid * 8);
#pragma unroll
    for (int i = 0; i < 4; ++i)
      async16(Bp + k0 + (size_t)i * 32 * EMBED, Bls + i * 2048 + tid * 8);
    __syncthreads();
    short8 af[4][2], bf[4][2];
#pragma unroll
    for (int mt = 0; mt < 4; ++mt)
#pragma unroll
      for (int kc = 0; kc < 2; ++kc)
        af[mt][kc] = *(const short8*)(Als + ab[kc] + mt * 1024);
#pragma unroll
    for (int nt = 0; nt < 4; ++nt)
#pragma unroll
      for (int kc = 0; kc < 2; ++kc)
        bf[nt][kc] = *(const short8*)(Bls + bb[kc] + nt * 1024);
#pragma unroll
    for (int kc = 0; kc < 2; ++kc)
#pragma unroll
      for (int mt = 0; mt < 4; ++mt)
#pragma unroll
        for (int nt = 0; nt < 4; ++nt)
          acc[mt][nt] = MFMA16(af[mt][kc], bf[nt][kc], acc[mt][nt]);
    __syncthreads();
  }

  const float* bsel = (n0 < 1024) ? bq : (n0 < 2048 ? bk : bv);
  const float scl = (n0 < 1024) ? ATT_SCALE : 1.0f;
  const int nb = n0 & 1023;
  float bias[4];
#pragma unroll
  for (int nt = 0; nt < 4; ++nt) bias[nt] = bsel[nb + wcol + nt * 16 + l16];
#pragma unroll
  for (int mt = 0; mt < 4; ++mt)
#pragma unroll
    for (int r = 0; r < 4; ++r) {
      int gm = m0 + wrow + mt * 16 + quad * 4 + r;
      size_t base = (size_t)gm * 3072 + n0 + wcol;
#pragma unroll
      for (int nt = 0; nt < 4; ++nt)
        C[base + nt * 16 + l16] = f2bf((acc[mt][nt][r] + bias[nt]) * scl);
    }
}

// ---------------- V[l][d] per (b,h) -> VT[b][h][d][l]  (plain transpose) ------
__global__ __launch_bounds__(256) void k_vt(const unsigned short* __restrict__ QKV,
                                            unsigned short* __restrict__ VT) {
  int lt = blockIdx.x;
  int bh = blockIdx.y;
  int b = bh >> 4, h = bh & 15;
  int l0 = lt * 64;
  __shared__ unsigned short tile[64][65];
  const unsigned short* src = QKV + (size_t)(b * SEQ) * 3072 + 2048 + h * 64;
  unsigned short* dst = VT + (size_t)bh * 64 * SEQ;
  int tid = threadIdx.x;
  for (int i = tid; i < 4096; i += 256) {
    int r = i >> 6, c = i & 63;
    tile[c][r] = src[(size_t)(l0 + r) * 3072 + c];
  }
  __syncthreads();
  for (int i = tid; i < 4096; i += 256) {
    int r = i >> 6, c = i & 63;                       // r: d, c: kv
    dst[(size_t)r * SEQ + l0 + c] = tile[r][c];
  }
}

// ---------------- attention v12: v10 structure, 32 q-rows/wave ----------------
// Occupancy via smaller per-wave state (NOT forced launch_bounds — R3 lesson:
// gfx950 unified VGPR/AGPR budget; forcing 4 waves/EU spilled the 64-reg
// accumulator, FETCH 24MB->892MB).  Halving q-rows/wave: acc 64->32 regs,
// qf 32->16, pa 32->16 => total ~142 <= 170 = 512/3, so (256,3) fits
// spill-free: 3 blocks/CU (LDS 33KB*3=99KB), 1.5x TLP vs R2.
// Grid doubles to (64,16); everything else identical to the R2 kernel.
__global__ __launch_bounds__(256, 3) void k_attn(const unsigned short* __restrict__ QKV,
                                                 const unsigned short* __restrict__ VT,
                                                 unsigned short* __restrict__ CTX) {
  const int bh = blockIdx.x, qt = blockIdx.y;
  const int b = bh >> 4, h = bh & 15;
  const int tid = threadIdx.x;
  const int w = tid >> 6, lane = tid & 63;
  const int l32 = lane & 31, hi = lane >> 5;

  __shared__ unsigned short Kls[2][64 * 64];   // [buf][kv][d]  xor-chunk swizzled
  __shared__ unsigned short Vls[2][64 * 64];   // [buf][d][kv]  xor-chunk swizzled
  __shared__ float rsls[4][32];                // per-wave row sums

  const unsigned short* Qb = QKV + (size_t)(b * SEQ + qt * 128 + w * 32) * 3072 + h * 64;
  const unsigned short* Kb = QKV + (size_t)(b * SEQ) * 3072 + 1024 + h * 64;
  const unsigned short* Vb = VT + (size_t)bh * 64 * SEQ;

  // Q fragments (B-operand of swapped QK): qf[ds] holds
  // Q[q = l32][d = ds*16 + hi*8 + j]  (pre-scaled by ATT_SCALE)
  short8 qf[4];
#pragma unroll
  for (int ds = 0; ds < 4; ++ds)
    qf[ds] = *(const short8*)(Qb + (size_t)l32 * 3072 + ds * 16 + hi * 8);

  floatx16 o[2];
  float rs = 0.f;
#pragma unroll
  for (int dg = 0; dg < 2; ++dg)
#pragma unroll
    for (int c = 0; c < 16; ++c) o[dg][c] = 0.f;

  const int srow = tid >> 3;                              // 0..31
  const int scol = (((tid & 7) ^ (srow & 7)) * 8);        // swizzled source chunk

  // prologue: stage kt=0 into buf 0
  async16(Kb + (size_t)srow * 3072 + scol, Kls[0] + tid * 8);
  async16(Kb + (size_t)(32 + srow) * 3072 + scol, Kls[0] + 2048 + tid * 8);
  async16(Vb + (size_t)srow * SEQ + scol, Vls[0] + tid * 8);
  async16(Vb + (size_t)(32 + srow) * SEQ + scol, Vls[0] + 2048 + tid * 8);
  __syncthreads();

  int cur = 0;
  for (int kt = 0; kt < 32; ++kt) {
    if (kt < 31) {                          // prefetch kt+1 into buf^1
      const int kn = (kt + 1) * 64;
      unsigned short* Kd = Kls[cur ^ 1];
      unsigned short* Vd = Vls[cur ^ 1];
      async16(Kb + (size_t)(kn + srow) * 3072 + scol, Kd + tid * 8);
      async16(Kb + (size_t)(kn + 32 + srow) * 3072 + scol, Kd + 2048 + tid * 8);
      async16(Vb + (size_t)srow * SEQ + kn + scol, Vd + tid * 8);
      async16(Vb + (size_t)(32 + srow) * SEQ + kn + scol, Vd + 2048 + tid * 8);
    }
    const unsigned short* Kc = Kls[cur];
    const unsigned short* Vc = Vls[cur];

    short8 pa[4];   // [ks] packed P fragments (PV A-operand)
#pragma unroll
    for (int kvg = 0; kvg < 2; ++kvg) {
      short8 kf[4];    // K A-frags: lane = kv-row kvg*32+l32, k = d-chunk
#pragma unroll
      for (int ds = 0; ds < 4; ++ds) {
        const int row = kvg * 32 + l32;
        kf[ds] = *(const short8*)(Kc + row * 64 + (((ds * 2 + hi) ^ (row & 7)) << 3));
      }
      floatx16 s;
#pragma unroll
      for (int c = 0; c < 16; ++c) s[c] = 0.f;
#pragma unroll
      for (int ds = 0; ds < 4; ++ds) s = MFMA32(kf[ds], qf[ds], s);
      float p[16];
#pragma unroll
      for (int c = 0; c < 16; ++c) p[c] = __builtin_amdgcn_exp2f(s[c]);
      rs += (((p[0] + p[1]) + (p[2] + p[3])) + ((p[4] + p[5]) + (p[6] + p[7])))
          + (((p[8] + p[9]) + (p[10] + p[11])) + ((p[12] + p[13]) + (p[14] + p[15])));
#pragma unroll
      for (int half = 0; half < 2; ++half) {   // ks = kvg*2 + half
        unsigned w0 = cvtpk(p[half * 8 + 0], p[half * 8 + 1]);
        unsigned w1 = cvtpk(p[half * 8 + 2], p[half * 8 + 3]);
        unsigned w2 = cvtpk(p[half * 8 + 4], p[half * 8 + 5]);
        unsigned w3 = cvtpk(p[half * 8 + 6], p[half * 8 + 7]);
        asm("v_permlane32_swap_b32 %0, %1" : "+v"(w0), "+v"(w2));
        asm("v_permlane32_swap_b32 %0, %1" : "+v"(w1), "+v"(w3));
        union { unsigned u[4]; short8 s8; } pk;
        pk.u[0] = w0; pk.u[1] = w1; pk.u[2] = w2; pk.u[3] = w3;
        pa[kvg * 2 + half] = pk.s8;
      }
    }

    // O += P V   (V B-frags: lane = d-col dg*32+l32, k = kv-chunk)
#pragma unroll
    for (int dg = 0; dg < 2; ++dg) {
      short8 vf[4];
#pragma unroll
      for (int ks = 0; ks < 4; ++ks) {
        const int row = dg * 32 + l32;
        vf[ks] = *(const short8*)(Vc + row * 64 + (((ks * 2 + hi) ^ (row & 7)) << 3));
      }
#pragma unroll
      for (int ks = 0; ks < 4; ++ks)
        o[dg] = MFMA32(pa[ks], vf[ks], o[dg]);
    }

    // single barrier: drains the prefetch after compute hid its latency,
    // and protects buf[cur^1] before the next iteration overwrites it
    __syncthreads();
    cur ^= 1;
  }

  // lanes l and l+32 hold the same q; combine, publish per-q sums via LDS
  rs += __shfl_xor(rs, 32);
  if (lane < 32) rsls[w][l32] = rs;
  // same-wave LDS readback; per-wave in-order, compiler inserts the lgkm wait

  // write ctx[b*SEQ + q][h*64 + d] bf16; O rows: q = (j&3)+8*(j>>2)+4*hi
#pragma unroll
  for (int j = 0; j < 16; ++j) {
    const int rl = (j & 3) + 8 * (j >> 2) + 4 * hi;
    const float inv = 1.f / rsls[w][rl];
    const int gq = b * SEQ + qt * 128 + w * 32 + rl;
    const size_t base = (size_t)gq * EMBED + h * 64;
#pragma unroll
    for (int dg = 0; dg < 2; ++dg)
      CTX[base + dg * 32 + l32] = f2bf(o[dg][j] * inv);
  }
}

// ---------------- proj GEMM + bias + residual -> fp32 x ----------------
__global__ __launch_bounds__(256) void k_gemm_proj(const unsigned short* __restrict__ A,
                                                   const unsigned short* __restrict__ BT,
                                                   const float* __restrict__ bp,
                                                   const float* __restrict__ hid,
                                                   float* __restrict__ X) {
  __shared__ unsigned short Als[128 * 64];
  __shared__ unsigned short Bls[128 * 64];
  const int tid = threadIdx.x;
  const int m0 = blockIdx.x * 128, n0 = blockIdx.y * 128;
  const int w = tid >> 6, lane = tid & 63, l16 = lane & 15, quad = lane >> 4;
  const int l7 = l16 & 7;
  const int wrow = (w >> 1) * 64, wcol = (w & 1) * 64;

  floatx4 acc[4][4];
#pragma unroll
  for (int i = 0; i < 4; ++i)
#pragma unroll
    for (int j = 0; j < 4; ++j) acc[i][j] = {0.f, 0.f, 0.f, 0.f};

  const int srow = tid >> 3;
  const int scol = (((tid & 7) ^ (srow & 7)) * 8);
  const unsigned short* Ap = A + (size_t)(m0 + srow) * EMBED + scol;
  const unsigned short* Bp = BT + (size_t)(n0 + srow) * EMBED + scol;

  int ab[2], bb[2];
#pragma unroll
  for (int kc = 0; kc < 2; ++kc) {
    ab[kc] = (wrow + l16) * 64 + (((4 * kc + quad) ^ l7) << 3);
    bb[kc] = (wcol + l16) * 64 + (((4 * kc + quad) ^ l7) << 3);
  }

  for (int kt = 0; kt < 16; ++kt) {
    const int k0 = kt * 64;
#pragma unroll
    for (int i = 0; i < 4; ++i)
      async16(Ap + k0 + (size_t)i * 32 * EMBED, Als + i * 2048 + tid * 8);
#pragma unroll
    for (int i = 0; i < 4; ++i)
      async16(Bp + k0 + (size_t)i * 32 * EMBED, Bls + i * 2048 + tid * 8);
    __syncthreads();
    short8 af[4][2], bf[4][2];
#pragma unroll
    for (int mt = 0; mt < 4; ++mt)
#pragma unroll
      for (int kc = 0; kc < 2; ++kc)
        af[mt][kc] = *(const short8*)(Als + ab[kc] + mt * 1024);
#pragma unroll
    for (int nt = 0; nt < 4; ++nt)
#pragma unroll
      for (int kc = 0; kc < 2; ++kc)
        bf[nt][kc] = *(const short8*)(Bls + bb[kc] + nt * 1024);
#pragma unroll
    for (int kc = 0; kc < 2; ++kc)
#pragma unroll
      for (int mt = 0; mt < 4; ++mt)
#pragma unroll
        for (int nt = 0; nt < 4; ++nt)
          acc[mt][nt] = MFMA16(af[mt][kc], bf[nt][kc], acc[mt][nt]);
    __syncthreads();
  }

  float bias[4];
#pragma unroll
  for (int nt = 0; nt < 4; ++nt) bias[nt] = bp[n0 + wcol + nt * 16 + l16];
#pragma unroll
  for (int mt = 0; mt < 4; ++mt)
#pragma unroll
    for (int r = 0; r < 4; ++r) {
      int gm = m0 + wrow + mt * 16 + quad * 4 + r;
      size_t base = (size_t)gm * EMBED + n0 + wcol;
#pragma unroll
      for (int nt = 0; nt < 4; ++nt) {
        size_t idx = base + nt * 16 + l16;
        X[idx] = acc[mt][nt][r] + bias[nt] + hid[idx];
      }
    }
}

// ---------------- in-place LayerNorm over E=1024, one block per row ----------------
__global__ __launch_bounds__(256) void k_ln(float* __restrict__ x,
                                            const float* __restrict__ gamma,
                                            const float* __restrict__ beta) {
  int row = blockIdx.x, tid = threadIdx.x;
  float4* rp = (float4*)(x + (size_t)row * EMBED);
  float4 v = rp[tid];
  float s = v.x + v.y + v.z + v.w;
  float q = v.x * v.x + v.y * v.y + v.z * v.z + v.w * v.w;
#pragma unroll
  for (int off = 1; off < 64; off <<= 1) {
    s += __shfl_xor(s, off);
    q += __shfl_xor(q, off);
  }
  __shared__ float ss[4], sq[4];
  int w = tid >> 6;
  if ((tid & 63) == 0) { ss[w] = s; sq[w] = q; }
  __syncthreads();
  s = ss[0] + ss[1] + ss[2] + ss[3];
  q = sq[0] + sq[1] + sq[2] + sq[3];
  float mean = s * (1.f / 1024.f);
  float var = q * (1.f / 1024.f) - mean * mean;
  float rstd = rsqrtf(var + 1e-8f);
  float4 g = ((const float4*)gamma)[tid];
  float4 be = ((const float4*)beta)[tid];
  v.x = (v.x - mean) * rstd * g.x + be.x;
  v.y = (v.y - mean) * rstd * g.y + be.y;
  v.z = (v.z - mean) * rstd * g.z + be.z;
  v.w = (v.w - mean) * rstd * g.w + be.w;
  rp[tid] = v;
}

extern "C" void kernel_launch(void* const* d_in, const int* in_sizes, int n_in,
                              void* d_out, int out_size, void* d_ws, size_t ws_size,
                              hipStream_t stream) {
  const float* hid   = (const float*)d_in[0];
  const float* Wq    = (const float*)d_in[1];
  const float* bq    = (const float*)d_in[2];
  const float* Wk    = (const float*)d_in[3];
  const float* bk    = (const float*)d_in[4];
  const float* Wv    = (const float*)d_in[5];
  const float* bv    = (const float*)d_in[6];
  const float* Wp    = (const float*)d_in[7];
  const float* bp    = (const float*)d_in[8];
  const float* gamma = (const float*)d_in[9];
  const float* beta  = (const float*)d_in[10];
  float* out = (float*)d_out;

  char* ws = (char*)d_ws;
  unsigned short* hidA = (unsigned short*)ws;                          // 16 MB  [8192][1024]
  unsigned short* WT   = (unsigned short*)(ws + (size_t)(16 << 20));   //  8 MB  [4096][1024]
  unsigned short* QKV  = (unsigned short*)(ws + (size_t)(24 << 20));   // 48 MB  [8192][3072]
  unsigned short* VT   = (unsigned short*)(ws + (size_t)(72 << 20));   // 16 MB  [64][64][2048]
  unsigned short* CTX  = (unsigned short*)(ws + (size_t)(88 << 20));   // 16 MB  [8192][1024]

  k_prep<<<5120, 256, 0, stream>>>(hid, hidA, Wq, Wk, Wv, Wp, WT);
  k_gemm_qkv<<<dim3(64, 24), 256, 0, stream>>>(hidA, WT, bq, bk, bv, QKV);
  k_vt<<<dim3(32, 64), 256, 0, stream>>>(QKV, VT);
  k_attn<<<dim3(64, 16), 256, 0, stream>>>(QKV, VT, CTX);
  k_gemm_proj<<<dim3(64, 8), 256, 0, stream>>>(CTX, WT + (size_t)3 * EMBED * EMBED, bp, hid, out);
  k_ln<<<8192, 256, 0, stream>>>(out, gamma, beta);
}

// Round 5
// 303.575 us; speedup vs baseline: 2.4659x; 1.0071x over previous
//
#include <hip/hip_runtime.h>

#define EMBED 1024
#define SEQ   2048
#define BATCH 4
#define HEADS 16

typedef __attribute__((ext_vector_type(8))) short short8;   // 8 bf16 in 4 VGPRs
typedef __attribute__((ext_vector_type(4))) float floatx4;
typedef __attribute__((ext_vector_type(16))) float floatx16;

#define MFMA16(a, b, c) __builtin_amdgcn_mfma_f32_16x16x32_bf16((a), (b), (c), 0, 0, 0)
#define MFMA32(a, b, c) __builtin_amdgcn_mfma_f32_32x32x16_bf16((a), (b), (c), 0, 0, 0)
#define ATT_SCALE (0.125f * 1.44269504088896340736f)   // 1/sqrt(64) * log2(e), folded into Q

static __device__ __forceinline__ unsigned short f2bf(float f) {
  union { float f; unsigned int u; } v; v.f = f;
  unsigned int u = v.u;
  u += 0x7fffu + ((u >> 16) & 1u);       // RNE
  return (unsigned short)(u >> 16);
}

// v_cvt_pk_bf16_f32: dst.lo16 = bf16(lo), dst.hi16 = bf16(hi)  (RNE)
static __device__ __forceinline__ unsigned cvtpk(float lo, float hi) {
  unsigned r;
  asm("v_cvt_pk_bf16_f32 %0, %1, %2" : "=v"(r) : "v"(lo), "v"(hi));
  return r;
}

static __device__ __forceinline__ void async16(const unsigned short* g, unsigned short* l) {
  __builtin_amdgcn_global_load_lds(
      (const __attribute__((address_space(1))) void*)g,
      (__attribute__((address_space(3))) void*)l, 16, 0, 0);
}

// ---------------- fused prep: hidden fp32->bf16 (blocks 0..4095) +
//                  W[k][n]->WT[n][k] bf16 for Wq,Wk,Wv,Wp (blocks 4096..5119) ---
__global__ __launch_bounds__(256) void k_prep(const float* __restrict__ hid,
                                              unsigned short* __restrict__ hidA,
                                              const float* __restrict__ Wq, const float* __restrict__ Wk,
                                              const float* __restrict__ Wv, const float* __restrict__ Wp,
                                              unsigned short* __restrict__ WT) {
  __shared__ unsigned short tile[64][65];
  const int bid = blockIdx.x, tid = threadIdx.x;
  if (bid < 4096) {                       // cvt: 8 floats / thread
    int i = bid * 256 + tid;
    const float4* s = (const float4*)hid;
    float4 a = s[i * 2], b = s[i * 2 + 1];
    uint4 o;
    o.x = (unsigned)f2bf(a.x) | ((unsigned)f2bf(a.y) << 16);
    o.y = (unsigned)f2bf(a.z) | ((unsigned)f2bf(a.w) << 16);
    o.z = (unsigned)f2bf(b.x) | ((unsigned)f2bf(b.y) << 16);
    o.w = (unsigned)f2bf(b.z) | ((unsigned)f2bf(b.w) << 16);
    ((uint4*)hidA)[i] = o;
    return;
  }
  const int idx = bid - 4096;
  const int z = idx >> 8, rem = idx & 255;
  const float* src = (z == 0) ? Wq : (z == 1) ? Wk : (z == 2) ? Wv : Wp;
  unsigned short* dst = WT + (size_t)z * EMBED * EMBED;
  const int k0 = (rem & 15) * 64, n0 = (rem >> 4) * 64;
  for (int i = tid; i < 4096; i += 256) {
    int r = i >> 6, c = i & 63;
    tile[c][r] = f2bf(src[(size_t)(k0 + r) * EMBED + n0 + c]);
  }
  __syncthreads();
  for (int i = tid; i < 4096; i += 256) {
    int r = i >> 6, c = i & 63;
    dst[(size_t)(n0 + r) * EMBED + k0 + c] = tile[r][c];
  }
}

// ---------------- QKV GEMM v2: 256x256 tile, 8 waves, deep-pipelined ----------
// C[m][n] = A[m][k]*BT[n][k] + bias, bf16 out; Q cols pre-scaled by ATT_SCALE.
// 4 sub-phases per K-tile (one 64x32-output quadrant each, 16 MFMA).  Tile t+1
// staged into buf^1 during t's sub-phases 0-1 (issue-to-use 3-4 phases); raw
// s_barrier (no implicit waitcnt drain - the m97 stall) + explicit lgkmcnt(0)
// per phase + single vmcnt(0) at tile boundary.  Safety: each wave's ds_reads
// are drained by its own lgkmcnt(0) before the phase-end barrier, and stages
// target the buffer last read before the previous tile boundary.
__global__ __launch_bounds__(512, 2) void k_gemm_qkv(const unsigned short* __restrict__ A,
                                                     const unsigned short* __restrict__ BT,
                                                     const float* __restrict__ bq,
                                                     const float* __restrict__ bk,
                                                     const float* __restrict__ bv,
                                                     unsigned short* __restrict__ C) {
  __shared__ unsigned short As[2][256 * 64];
  __shared__ unsigned short Bs[2][256 * 64];
  const int tid = threadIdx.x;
  const int m0 = blockIdx.x * 256, n0 = blockIdx.y * 256;
  const int w = tid >> 6, lane = tid & 63, l16 = lane & 15, quad = lane >> 4;
  const int wm = w >> 2, wn = w & 3;            // wave grid 2M x 4N, 128x64 out/wave

  floatx4 acc[8][4];
#pragma unroll
  for (int i = 0; i < 8; ++i)
#pragma unroll
    for (int j = 0; j < 4; ++j) acc[i][j] = {0.f, 0.f, 0.f, 0.f};

  // staging: 512 threads, srow 0..63, 8 swizzled col-chunks; 4 rounds of 64 rows
  // cover 256 rows per operand per K-tile (8 async16/thread/tile).
  const int srow = tid >> 3;
  const int scol = (((tid & 7) ^ (srow & 7)) * 8);
  const unsigned short* Ag = A + (size_t)(m0 + srow) * EMBED + scol;
  const unsigned short* Bg = BT + (size_t)(n0 + srow) * EMBED + scol;

  unsigned short* Acur = As[0];
  unsigned short* Bcur = Bs[0];
  unsigned short* Anxt = As[1];
  unsigned short* Bnxt = Bs[1];

  // prologue: stage tile 0 into buf0
#pragma unroll
  for (int r = 0; r < 4; ++r) async16(Ag + (size_t)r * 64 * EMBED, Acur + r * 4096 + tid * 8);
#pragma unroll
  for (int r = 0; r < 4; ++r) async16(Bg + (size_t)r * 64 * EMBED, Bcur + r * 4096 + tid * 8);
  __asm__ volatile("s_waitcnt vmcnt(0)" ::: "memory");
  __asm__ volatile("s_barrier" ::: "memory");

  for (int t = 0; t < 16; ++t) {
    const int last = (t == 15);
#pragma unroll
    for (int q = 0; q < 4; ++q) {
      const int mh = q >> 1, nh = q & 1;
      if (q == 0 && !last) {
        const unsigned short* Asrc = Ag + (t + 1) * 64;
#pragma unroll
        for (int r = 0; r < 4; ++r) async16(Asrc + (size_t)r * 64 * EMBED, Anxt + r * 4096 + tid * 8);
      }
      if (q == 1 && !last) {
        const unsigned short* Bsrc = Bg + (t + 1) * 64;
#pragma unroll
        for (int r = 0; r < 4; ++r) async16(Bsrc + (size_t)r * 64 * EMBED, Bnxt + r * 4096 + tid * 8);
      }
      short8 af[4][2], bf[2][2];
#pragma unroll
      for (int mi = 0; mi < 4; ++mi)
#pragma unroll
        for (int kc = 0; kc < 2; ++kc) {
          const int row = wm * 128 + (mh * 4 + mi) * 16 + l16;
          af[mi][kc] = *(const short8*)(Acur + row * 64 + (((kc * 4 + quad) ^ (row & 7)) << 3));
        }
#pragma unroll
      for (int ni = 0; ni < 2; ++ni)
#pragma unroll
        for (int kc = 0; kc < 2; ++kc) {
          const int row = wn * 64 + (nh * 2 + ni) * 16 + l16;
          bf[ni][kc] = *(const short8*)(Bcur + row * 64 + (((kc * 4 + quad) ^ (row & 7)) << 3));
        }
      __asm__ volatile("s_barrier" ::: "memory");
      __asm__ volatile("s_waitcnt lgkmcnt(0)" ::: "memory");
      __builtin_amdgcn_sched_barrier(0);
      __builtin_amdgcn_s_setprio(1);
#pragma unroll
      for (int kc = 0; kc < 2; ++kc)
#pragma unroll
        for (int mi = 0; mi < 4; ++mi)
#pragma unroll
          for (int ni = 0; ni < 2; ++ni)
            acc[mh * 4 + mi][nh * 2 + ni] =
                MFMA16(af[mi][kc], bf[ni][kc], acc[mh * 4 + mi][nh * 2 + ni]);
      __builtin_amdgcn_s_setprio(0);
      if (q == 3) __asm__ volatile("s_waitcnt vmcnt(0)" ::: "memory");
      __asm__ volatile("s_barrier" ::: "memory");
    }
    unsigned short* tp;
    tp = Acur; Acur = Anxt; Anxt = tp;
    tp = Bcur; Bcur = Bnxt; Bnxt = tp;
  }

  const float* bsel = (n0 < 1024) ? bq : (n0 < 2048 ? bk : bv);
  const float scl = (n0 < 1024) ? ATT_SCALE : 1.0f;
  const int nb = n0 & 1023;
  float bias[4];
#pragma unroll
  for (int nt = 0; nt < 4; ++nt) bias[nt] = bsel[nb + wn * 64 + nt * 16 + l16];
#pragma unroll
  for (int mt = 0; mt < 8; ++mt)
#pragma unroll
    for (int r = 0; r < 4; ++r) {
      const int gm = m0 + wm * 128 + mt * 16 + quad * 4 + r;
      const size_t base = (size_t)gm * 3072 + n0 + wn * 64;
#pragma unroll
      for (int nt = 0; nt < 4; ++nt)
        C[base + nt * 16 + l16] = f2bf((acc[mt][nt][r] + bias[nt]) * scl);
    }
}

// ---------------- V[l][d] per (b,h) -> VT[b][h][d][l]  (plain transpose) ------
__global__ __launch_bounds__(256) void k_vt(const unsigned short* __restrict__ QKV,
                                            unsigned short* __restrict__ VT) {
  int lt = blockIdx.x;
  int bh = blockIdx.y;
  int b = bh >> 4, h = bh & 15;
  int l0 = lt * 64;
  __shared__ unsigned short tile[64][65];
  const unsigned short* src = QKV + (size_t)(b * SEQ) * 3072 + 2048 + h * 64;
  unsigned short* dst = VT + (size_t)bh * 64 * SEQ;
  int tid = threadIdx.x;
  for (int i = tid; i < 4096; i += 256) {
    int r = i >> 6, c = i & 63;
    tile[c][r] = src[(size_t)(l0 + r) * 3072 + c];
  }
  __syncthreads();
  for (int i = tid; i < 4096; i += 256) {
    int r = i >> 6, c = i & 63;                       // r: d, c: kv
    dst[(size_t)r * SEQ + l0 + c] = tile[r][c];
  }
}

// ---------------- attention v10 (R2 verbatim - best measured: 76.5us) ---------
// 32x32 swapped QK^T, P fully in registers via cvt_pk + permlane32_swap.
// 64 q-rows/wave, K/V double-buffered, single end barrier.  R4 taught us:
// halving q-rows/wave for occupancy doubles staging per MFMA and regresses.
__global__ __launch_bounds__(256, 2) void k_attn(const unsigned short* __restrict__ QKV,
                                                 const unsigned short* __restrict__ VT,
                                                 unsigned short* __restrict__ CTX) {
  const int bh = blockIdx.x, qt = blockIdx.y;
  const int b = bh >> 4, h = bh & 15;
  const int tid = threadIdx.x;
  const int w = tid >> 6, lane = tid & 63;
  const int l32 = lane & 31, hi = lane >> 5;

  __shared__ unsigned short Kls[2][64 * 64];   // [buf][kv][d]  xor-chunk swizzled
  __shared__ unsigned short Vls[2][64 * 64];   // [buf][d][kv]  xor-chunk swizzled
  __shared__ float rsls[4][64];                // per-wave row sums

  const unsigned short* Qb = QKV + (size_t)(b * SEQ + qt * 256 + w * 64) * 3072 + h * 64;
  const unsigned short* Kb = QKV + (size_t)(b * SEQ) * 3072 + 1024 + h * 64;
  const unsigned short* Vb = VT + (size_t)bh * 64 * SEQ;

  // Q fragments (B-operand of swapped QK): qf[qg][ds] holds
  // Q[q = qg*32 + l32][d = ds*16 + hi*8 + j]  (pre-scaled by ATT_SCALE)
  short8 qf[2][4];
#pragma unroll
  for (int qg = 0; qg < 2; ++qg)
#pragma unroll
    for (int ds = 0; ds < 4; ++ds)
      qf[qg][ds] = *(const short8*)(Qb + (size_t)(qg * 32 + l32) * 3072 + ds * 16 + hi * 8);

  floatx16 o[2][2];
  float rs[2] = {0.f, 0.f};
#pragma unroll
  for (int qg = 0; qg < 2; ++qg)
#pragma unroll
    for (int dg = 0; dg < 2; ++dg)
#pragma unroll
      for (int c = 0; c < 16; ++c) o[qg][dg][c] = 0.f;

  const int srow = tid >> 3;                              // 0..31
  const int scol = (((tid & 7) ^ (srow & 7)) * 8);        // swizzled source chunk

  // prologue: stage kt=0 into buf 0
  async16(Kb + (size_t)srow * 3072 + scol, Kls[0] + tid * 8);
  async16(Kb + (size_t)(32 + srow) * 3072 + scol, Kls[0] + 2048 + tid * 8);
  async16(Vb + (size_t)srow * SEQ + scol, Vls[0] + tid * 8);
  async16(Vb + (size_t)(32 + srow) * SEQ + scol, Vls[0] + 2048 + tid * 8);
  __syncthreads();

  int cur = 0;
  for (int kt = 0; kt < 32; ++kt) {
    if (kt < 31) {                          // prefetch kt+1 into buf^1
      const int kn = (kt + 1) * 64;
      unsigned short* Kd = Kls[cur ^ 1];
      unsigned short* Vd = Vls[cur ^ 1];
      async16(Kb + (size_t)(kn + srow) * 3072 + scol, Kd + tid * 8);
      async16(Kb + (size_t)(kn + 32 + srow) * 3072 + scol, Kd + 2048 + tid * 8);
      async16(Vb + (size_t)srow * SEQ + kn + scol, Vd + tid * 8);
      async16(Vb + (size_t)(32 + srow) * SEQ + kn + scol, Vd + 2048 + tid * 8);
    }
    const unsigned short* Kc = Kls[cur];
    const unsigned short* Vc = Vls[cur];

    short8 pa[2][4];   // [qg][ks] packed P fragments (PV A-operand)
#pragma unroll
    for (int kvg = 0; kvg < 2; ++kvg) {
      short8 kf[4];    // K A-frags: lane = kv-row kvg*32+l32, k = d-chunk
#pragma unroll
      for (int ds = 0; ds < 4; ++ds) {
        const int row = kvg * 32 + l32;
        kf[ds] = *(const short8*)(Kc + row * 64 + (((ds * 2 + hi) ^ (row & 7)) << 3));
      }
#pragma unroll
      for (int qg = 0; qg < 2; ++qg) {
        floatx16 s;
#pragma unroll
        for (int c = 0; c < 16; ++c) s[c] = 0.f;
#pragma unroll
        for (int ds = 0; ds < 4; ++ds) s = MFMA32(kf[ds], qf[qg][ds], s);
        float p[16];
#pragma unroll
        for (int c = 0; c < 16; ++c) p[c] = __builtin_amdgcn_exp2f(s[c]);
        rs[qg] += (((p[0] + p[1]) + (p[2] + p[3])) + ((p[4] + p[5]) + (p[6] + p[7])))
                + (((p[8] + p[9]) + (p[10] + p[11])) + ((p[12] + p[13]) + (p[14] + p[15])));
#pragma unroll
        for (int half = 0; half < 2; ++half) {   // ks = kvg*2 + half
          unsigned w0 = cvtpk(p[half * 8 + 0], p[half * 8 + 1]);
          unsigned w1 = cvtpk(p[half * 8 + 2], p[half * 8 + 3]);
          unsigned w2 = cvtpk(p[half * 8 + 4], p[half * 8 + 5]);
          unsigned w3 = cvtpk(p[half * 8 + 6], p[half * 8 + 7]);
          asm("v_permlane32_swap_b32 %0, %1" : "+v"(w0), "+v"(w2));
          asm("v_permlane32_swap_b32 %0, %1" : "+v"(w1), "+v"(w3));
          union { unsigned u[4]; short8 s8; } pk;
          pk.u[0] = w0; pk.u[1] = w1; pk.u[2] = w2; pk.u[3] = w3;
          pa[qg][kvg * 2 + half] = pk.s8;
        }
      }
    }

    // O += P V   (V B-frags: lane = d-col dg*32+l32, k = kv-chunk)
#pragma unroll
    for (int dg = 0; dg < 2; ++dg) {
      short8 vf[4];
#pragma unroll
      for (int ks = 0; ks < 4; ++ks) {
        const int row = dg * 32 + l32;
        vf[ks] = *(const short8*)(Vc + row * 64 + (((ks * 2 + hi) ^ (row & 7)) << 3));
      }
#pragma unroll
      for (int qg = 0; qg < 2; ++qg)
#pragma unroll
        for (int ks = 0; ks < 4; ++ks)
          o[qg][dg] = MFMA32(pa[qg][ks], vf[ks], o[qg][dg]);
    }

    // single barrier: drains the prefetch after compute hid its latency,
    // and protects buf[cur^1] before kt+1 overwrites it
    __syncthreads();
    cur ^= 1;
  }

  // lanes l and l+32 hold the same q; combine, publish per-q sums via LDS
  rs[0] += __shfl_xor(rs[0], 32);
  rs[1] += __shfl_xor(rs[1], 32);
  if (lane < 32) {
    rsls[w][l32] = rs[0];
    rsls[w][32 + l32] = rs[1];
  }
  // same-wave LDS readback; per-wave in-order, compiler inserts the lgkm wait

  // write ctx[b*SEQ + q][h*64 + d] bf16; O rows: q = (j&3)+8*(j>>2)+4*hi (+32qg)
#pragma unroll
  for (int qg = 0; qg < 2; ++qg)
#pragma unroll
    for (int j = 0; j < 16; ++j) {
      const int rl = (j & 3) + 8 * (j >> 2) + 4 * hi;
      const float inv = 1.f / rsls[w][qg * 32 + rl];
      const int gq = b * SEQ + qt * 256 + w * 64 + qg * 32 + rl;
      const size_t base = (size_t)gq * EMBED + h * 64;
#pragma unroll
      for (int dg = 0; dg < 2; ++dg)
        CTX[base + dg * 32 + l32] = f2bf(o[qg][dg][j] * inv);
    }
}

// ---------------- proj GEMM + bias + residual -> fp32 x ----------------
__global__ __launch_bounds__(256) void k_gemm_proj(const unsigned short* __restrict__ A,
                                                   const unsigned short* __restrict__ BT,
                                                   const float* __restrict__ bp,
                                                   const float* __restrict__ hid,
                                                   float* __restrict__ X) {
  __shared__ unsigned short Als[128 * 64];
  __shared__ unsigned short Bls[128 * 64];
  const int tid = threadIdx.x;
  const int m0 = blockIdx.x * 128, n0 = blockIdx.y * 128;
  const int w = tid >> 6, lane = tid & 63, l16 = lane & 15, quad = lane >> 4;
  const int l7 = l16 & 7;
  const int wrow = (w >> 1) * 64, wcol = (w & 1) * 64;

  floatx4 acc[4][4];
#pragma unroll
  for (int i = 0; i < 4; ++i)
#pragma unroll
    for (int j = 0; j < 4; ++j) acc[i][j] = {0.f, 0.f, 0.f, 0.f};

  const int srow = tid >> 3;
  const int scol = (((tid & 7) ^ (srow & 7)) * 8);
  const unsigned short* Ap = A + (size_t)(m0 + srow) * EMBED + scol;
  const unsigned short* Bp = BT + (size_t)(n0 + srow) * EMBED + scol;

  int ab[2], bb[2];
#pragma unroll
  for (int kc = 0; kc < 2; ++kc) {
    ab[kc] = (wrow + l16) * 64 + (((4 * kc + quad) ^ l7) << 3);
    bb[kc] = (wcol + l16) * 64 + (((4 * kc + quad) ^ l7) << 3);
  }

  for (int kt = 0; kt < 16; ++kt) {
    const int k0 = kt * 64;
#pragma unroll
    for (int i = 0; i < 4; ++i)
      async16(Ap + k0 + (size_t)i * 32 * EMBED, Als + i * 2048 + tid * 8);
#pragma unroll
    for (int i = 0; i < 4; ++i)
      async16(Bp + k0 + (size_t)i * 32 * EMBED, Bls + i * 2048 + tid * 8);
    __syncthreads();
    short8 af[4][2], bf[4][2];
#pragma unroll
    for (int mt = 0; mt < 4; ++mt)
#pragma unroll
      for (int kc = 0; kc < 2; ++kc)
        af[mt][kc] = *(const short8*)(Als + ab[kc] + mt * 1024);
#pragma unroll
    for (int nt = 0; nt < 4; ++nt)
#pragma unroll
      for (int kc = 0; kc < 2; ++kc)
        bf[nt][kc] = *(const short8*)(Bls + bb[kc] + nt * 1024);
#pragma unroll
    for (int kc = 0; kc < 2; ++kc)
#pragma unroll
      for (int mt = 0; mt < 4; ++mt)
#pragma unroll
        for (int nt = 0; nt < 4; ++nt)
          acc[mt][nt] = MFMA16(af[mt][kc], bf[nt][kc], acc[mt][nt]);
    __syncthreads();
  }

  float bias[4];
#pragma unroll
  for (int nt = 0; nt < 4; ++nt) bias[nt] = bp[n0 + wcol + nt * 16 + l16];
#pragma unroll
  for (int mt = 0; mt < 4; ++mt)
#pragma unroll
    for (int r = 0; r < 4; ++r) {
      int gm = m0 + wrow + mt * 16 + quad * 4 + r;
      size_t base = (size_t)gm * EMBED + n0 + wcol;
#pragma unroll
      for (int nt = 0; nt < 4; ++nt) {
        size_t idx = base + nt * 16 + l16;
        X[idx] = acc[mt][nt][r] + bias[nt] + hid[idx];
      }
    }
}

// ---------------- in-place LayerNorm over E=1024, one block per row ----------------
__global__ __launch_bounds__(256) void k_ln(float* __restrict__ x,
                                            const float* __restrict__ gamma,
                                            const float* __restrict__ beta) {
  int row = blockIdx.x, tid = threadIdx.x;
  float4* rp = (float4*)(x + (size_t)row * EMBED);
  float4 v = rp[tid];
  float s = v.x + v.y + v.z + v.w;
  float q = v.x * v.x + v.y * v.y + v.z * v.z + v.w * v.w;
#pragma unroll
  for (int off = 1; off < 64; off <<= 1) {
    s += __shfl_xor(s, off);
    q += __shfl_xor(q, off);
  }
  __shared__ float ss[4], sq[4];
  int w = tid >> 6;
  if ((tid & 63) == 0) { ss[w] = s; sq[w] = q; }
  __syncthreads();
  s = ss[0] + ss[1] + ss[2] + ss[3];
  q = sq[0] + sq[1] + sq[2] + sq[3];
  float mean = s * (1.f / 1024.f);
  float var = q * (1.f / 1024.f) - mean * mean;
  float rstd = rsqrtf(var + 1e-8f);
  float4 g = ((const float4*)gamma)[tid];
  float4 be = ((const float4*)beta)[tid];
  v.x = (v.x - mean) * rstd * g.x + be.x;
  v.y = (v.y - mean) * rstd * g.y + be.y;
  v.z = (v.z - mean) * rstd * g.z + be.z;
  v.w = (v.w - mean) * rstd * g.w + be.w;
  rp[tid] = v;
}

extern "C" void kernel_launch(void* const* d_in, const int* in_sizes, int n_in,
                              void* d_out, int out_size, void* d_ws, size_t ws_size,
                              hipStream_t stream) {
  const float* hid   = (const float*)d_in[0];
  const float* Wq    = (const float*)d_in[1];
  const float* bq    = (const float*)d_in[2];
  const float* Wk    = (const float*)d_in[3];
  const float* bk    = (const float*)d_in[4];
  const float* Wv    = (const float*)d_in[5];
  const float* bv    = (const float*)d_in[6];
  const float* Wp    = (const float*)d_in[7];
  const float* bp    = (const float*)d_in[8];
  const float* gamma = (const float*)d_in[9];
  const float* beta  = (const float*)d_in[10];
  float* out = (float*)d_out;

  char* ws = (char*)d_ws;
  unsigned short* hidA = (unsigned short*)ws;                          // 16 MB  [8192][1024]
  unsigned short* WT   = (unsigned short*)(ws + (size_t)(16 << 20));   //  8 MB  [4096][1024]
  unsigned short* QKV  = (unsigned short*)(ws + (size_t)(24 << 20));   // 48 MB  [8192][3072]
  unsigned short* VT   = (unsigned short*)(ws + (size_t)(72 << 20));   // 16 MB  [64][64][2048]
  unsigned short* CTX  = (unsigned short*)(ws + (size_t)(88 << 20));   // 16 MB  [8192][1024]

  k_prep<<<5120, 256, 0, stream>>>(hid, hidA, Wq, Wk, Wv, Wp, WT);
  k_gemm_qkv<<<dim3(32, 12), 512, 0, stream>>>(hidA, WT, bq, bk, bv, QKV);
  k_vt<<<dim3(32, 64), 256, 0, stream>>>(QKV, VT);
  k_attn<<<dim3(64, 8), 256, 0, stream>>>(QKV, VT, CTX);
  k_gemm_proj<<<dim3(64, 8), 256, 0, stream>>>(CTX, WT + (size_t)3 * EMBED * EMBED, bp, hid, out);
  k_ln<<<8192, 256, 0, stream>>>(out, gamma, beta);
}

// Round 6
// 278.350 us; speedup vs baseline: 2.6894x; 1.0906x over previous
//
#include <hip/hip_runtime.h>

#define EMBED 1024
#define SEQ   2048
#define BATCH 4
#define HEADS 16

typedef __attribute__((ext_vector_type(8))) short short8;   // 8 bf16 in 4 VGPRs
typedef __attribute__((ext_vector_type(4))) float floatx4;
typedef __attribute__((ext_vector_type(16))) float floatx16;

#define MFMA16(a, b, c) __builtin_amdgcn_mfma_f32_16x16x32_bf16((a), (b), (c), 0, 0, 0)
#define MFMA32(a, b, c) __builtin_amdgcn_mfma_f32_32x32x16_bf16((a), (b), (c), 0, 0, 0)
#define ATT_SCALE (0.125f * 1.44269504088896340736f)   // 1/sqrt(64) * log2(e), folded into Q

static __device__ __forceinline__ unsigned short f2bf(float f) {
  union { float f; unsigned int u; } v; v.f = f;
  unsigned int u = v.u;
  u += 0x7fffu + ((u >> 16) & 1u);       // RNE
  return (unsigned short)(u >> 16);
}

// v_cvt_pk_bf16_f32: dst.lo16 = bf16(lo), dst.hi16 = bf16(hi)  (RNE)
static __device__ __forceinline__ unsigned cvtpk(float lo, float hi) {
  unsigned r;
  asm("v_cvt_pk_bf16_f32 %0, %1, %2" : "=v"(r) : "v"(lo), "v"(hi));
  return r;
}

static __device__ __forceinline__ void async16(const unsigned short* g, unsigned short* l) {
  __builtin_amdgcn_global_load_lds(
      (const __attribute__((address_space(1))) void*)g,
      (__attribute__((address_space(3))) void*)l, 16, 0, 0);
}

// ---------------- fused prep: hidden fp32->bf16 (blocks 0..4095) +
//                  W[k][n]->WT[n][k] bf16 for Wq,Wk,Wv,Wp (blocks 4096..5119) ---
__global__ __launch_bounds__(256) void k_prep(const float* __restrict__ hid,
                                              unsigned short* __restrict__ hidA,
                                              const float* __restrict__ Wq, const float* __restrict__ Wk,
                                              const float* __restrict__ Wv, const float* __restrict__ Wp,
                                              unsigned short* __restrict__ WT) {
  __shared__ unsigned short tile[64][65];
  const int bid = blockIdx.x, tid = threadIdx.x;
  if (bid < 4096) {                       // cvt: 8 floats / thread
    int i = bid * 256 + tid;
    const float4* s = (const float4*)hid;
    float4 a = s[i * 2], b = s[i * 2 + 1];
    uint4 o;
    o.x = (unsigned)f2bf(a.x) | ((unsigned)f2bf(a.y) << 16);
    o.y = (unsigned)f2bf(a.z) | ((unsigned)f2bf(a.w) << 16);
    o.z = (unsigned)f2bf(b.x) | ((unsigned)f2bf(b.y) << 16);
    o.w = (unsigned)f2bf(b.z) | ((unsigned)f2bf(b.w) << 16);
    ((uint4*)hidA)[i] = o;
    return;
  }
  const int idx = bid - 4096;
  const int z = idx >> 8, rem = idx & 255;
  const float* src = (z == 0) ? Wq : (z == 1) ? Wk : (z == 2) ? Wv : Wp;
  unsigned short* dst = WT + (size_t)z * EMBED * EMBED;
  const int k0 = (rem & 15) * 64, n0 = (rem >> 4) * 64;
  for (int i = tid; i < 4096; i += 256) {
    int r = i >> 6, c = i & 63;
    tile[c][r] = f2bf(src[(size_t)(k0 + r) * EMBED + n0 + c]);
  }
  __syncthreads();
  for (int i = tid; i < 4096; i += 256) {
    int r = i >> 6, c = i & 63;
    dst[(size_t)(n0 + r) * EMBED + k0 + c] = tile[r][c];
  }
}

// ---------------- QKV GEMM (128x128, proven structure) + fused V-transpose ----
// by < 16 : C[m][n0..] = hidA[m,:].WT_qk[n,:] + bias  (Q cols pre-scaled), m over
//           8192, n over 2048 (Q,K only) -> QKV.
// by >= 16: V^T by operand symmetry: rows = d (WvT rows, 1024), cols = l (hidA
//           rows, 8192); bias bv[d] per-ROW; writes VT[b*16+h][d][l] directly.
//           Same FLOP as the old V third + k_vt kernel deleted (-32MB traffic).
// R5 lesson: 256^2 tile => 1 block/CU lockstep + 384-block imbalance = 22%
// MfmaUtil.  This 128^2 2-barrier structure is the measured local optimum.
__global__ __launch_bounds__(256) void k_gemm_qkv(const unsigned short* __restrict__ A,
                                                  const unsigned short* __restrict__ BT,
                                                  const float* __restrict__ bq,
                                                  const float* __restrict__ bk,
                                                  const float* __restrict__ bv,
                                                  unsigned short* __restrict__ C,
                                                  unsigned short* __restrict__ VT) {
  __shared__ unsigned short Als[128 * 64];
  __shared__ unsigned short Bls[128 * 64];
  const int tid = threadIdx.x;
  const int by = blockIdx.y;
  const bool vmode = (by >= 16);
  const int arow0 = vmode ? (by - 16) * 128 : blockIdx.x * 128;
  const int brow0 = vmode ? blockIdx.x * 128 : by * 128;
  const int w = tid >> 6, lane = tid & 63, l16 = lane & 15, quad = lane >> 4;
  const int l7 = l16 & 7;
  const int wrow = (w >> 1) * 64, wcol = (w & 1) * 64;

  floatx4 acc[4][4];
#pragma unroll
  for (int i = 0; i < 4; ++i)
#pragma unroll
    for (int j = 0; j < 4; ++j) acc[i][j] = {0.f, 0.f, 0.f, 0.f};

  const int srow = tid >> 3;
  const int scol = (((tid & 7) ^ (srow & 7)) * 8);
  const unsigned short* Arow = vmode ? (BT + (size_t)2 * EMBED * EMBED) : A;
  const unsigned short* Brow = vmode ? A : BT;
  const unsigned short* Ap = Arow + (size_t)(arow0 + srow) * EMBED + scol;
  const unsigned short* Bp = Brow + (size_t)(brow0 + srow) * EMBED + scol;

  int ab[2], bb[2];
#pragma unroll
  for (int kc = 0; kc < 2; ++kc) {
    ab[kc] = (wrow + l16) * 64 + (((4 * kc + quad) ^ l7) << 3);
    bb[kc] = (wcol + l16) * 64 + (((4 * kc + quad) ^ l7) << 3);
  }

  for (int kt = 0; kt < 16; ++kt) {
    const int k0 = kt * 64;
#pragma unroll
    for (int i = 0; i < 4; ++i)
      async16(Ap + k0 + (size_t)i * 32 * EMBED, Als + i * 2048 + tid * 8);
#pragma unroll
    for (int i = 0; i < 4; ++i)
      async16(Bp + k0 + (size_t)i * 32 * EMBED, Bls + i * 2048 + tid * 8);
    __syncthreads();
    short8 af[4][2], bf[4][2];
#pragma unroll
    for (int mt = 0; mt < 4; ++mt)
#pragma unroll
      for (int kc = 0; kc < 2; ++kc)
        af[mt][kc] = *(const short8*)(Als + ab[kc] + mt * 1024);
#pragma unroll
    for (int nt = 0; nt < 4; ++nt)
#pragma unroll
      for (int kc = 0; kc < 2; ++kc)
        bf[nt][kc] = *(const short8*)(Bls + bb[kc] + nt * 1024);
#pragma unroll
    for (int kc = 0; kc < 2; ++kc)
#pragma unroll
      for (int mt = 0; mt < 4; ++mt)
#pragma unroll
        for (int nt = 0; nt < 4; ++nt)
          acc[mt][nt] = MFMA16(af[mt][kc], bf[nt][kc], acc[mt][nt]);
    __syncthreads();
  }

  if (!vmode) {
    const int n0 = brow0;
    const float* bsel = (n0 < 1024) ? bq : bk;
    const float scl = (n0 < 1024) ? ATT_SCALE : 1.0f;
    const int nb = n0 & 1023;
    float bias[4];
#pragma unroll
    for (int nt = 0; nt < 4; ++nt) bias[nt] = bsel[nb + wcol + nt * 16 + l16];
#pragma unroll
    for (int mt = 0; mt < 4; ++mt)
#pragma unroll
      for (int r = 0; r < 4; ++r) {
        int gm = arow0 + wrow + mt * 16 + quad * 4 + r;
        size_t base = (size_t)gm * 3072 + n0 + wcol;
#pragma unroll
        for (int nt = 0; nt < 4; ++nt)
          C[base + nt * 16 + l16] = f2bf((acc[mt][nt][r] + bias[nt]) * scl);
      }
  } else {
    // rows = d-global, cols = l-global; VT[(b*16+h)*64 + d][l]
#pragma unroll
    for (int mt = 0; mt < 4; ++mt)
#pragma unroll
      for (int r = 0; r < 4; ++r) {
        const int drow = arow0 + wrow + mt * 16 + quad * 4 + r;   // 0..1023
        const float bias = bv[drow];
        const int cg0 = brow0 + wcol;                             // col base (l-global)
        const int b = cg0 >> 11;                                  // constant per block
        const size_t base = ((size_t)((b * 16 + (drow >> 6)) * 64 + (drow & 63))) * SEQ
                            + (cg0 & 2047);
#pragma unroll
        for (int nt = 0; nt < 4; ++nt)
          VT[base + nt * 16 + l16] = f2bf(acc[mt][nt][r] + bias);
      }
  }
}

// ---------------- attention v10 (R2 verbatim - best measured: 76.5us) ---------
// 32x32 swapped QK^T, P fully in registers via cvt_pk + permlane32_swap.
// 64 q-rows/wave, K/V double-buffered, single end barrier.  R4 taught us:
// halving q-rows/wave for occupancy doubles staging per MFMA and regresses.
__global__ __launch_bounds__(256, 2) void k_attn(const unsigned short* __restrict__ QKV,
                                                 const unsigned short* __restrict__ VT,
                                                 unsigned short* __restrict__ CTX) {
  const int bh = blockIdx.x, qt = blockIdx.y;
  const int b = bh >> 4, h = bh & 15;
  const int tid = threadIdx.x;
  const int w = tid >> 6, lane = tid & 63;
  const int l32 = lane & 31, hi = lane >> 5;

  __shared__ unsigned short Kls[2][64 * 64];   // [buf][kv][d]  xor-chunk swizzled
  __shared__ unsigned short Vls[2][64 * 64];   // [buf][d][kv]  xor-chunk swizzled
  __shared__ float rsls[4][64];                // per-wave row sums

  const unsigned short* Qb = QKV + (size_t)(b * SEQ + qt * 256 + w * 64) * 3072 + h * 64;
  const unsigned short* Kb = QKV + (size_t)(b * SEQ) * 3072 + 1024 + h * 64;
  const unsigned short* Vb = VT + (size_t)bh * 64 * SEQ;

  // Q fragments (B-operand of swapped QK): qf[qg][ds] holds
  // Q[q = qg*32 + l32][d = ds*16 + hi*8 + j]  (pre-scaled by ATT_SCALE)
  short8 qf[2][4];
#pragma unroll
  for (int qg = 0; qg < 2; ++qg)
#pragma unroll
    for (int ds = 0; ds < 4; ++ds)
      qf[qg][ds] = *(const short8*)(Qb + (size_t)(qg * 32 + l32) * 3072 + ds * 16 + hi * 8);

  floatx16 o[2][2];
  float rs[2] = {0.f, 0.f};
#pragma unroll
  for (int qg = 0; qg < 2; ++qg)
#pragma unroll
    for (int dg = 0; dg < 2; ++dg)
#pragma unroll
      for (int c = 0; c < 16; ++c) o[qg][dg][c] = 0.f;

  const int srow = tid >> 3;                              // 0..31
  const int scol = (((tid & 7) ^ (srow & 7)) * 8);        // swizzled source chunk

  // prologue: stage kt=0 into buf 0
  async16(Kb + (size_t)srow * 3072 + scol, Kls[0] + tid * 8);
  async16(Kb + (size_t)(32 + srow) * 3072 + scol, Kls[0] + 2048 + tid * 8);
  async16(Vb + (size_t)srow * SEQ + scol, Vls[0] + tid * 8);
  async16(Vb + (size_t)(32 + srow) * SEQ + scol, Vls[0] + 2048 + tid * 8);
  __syncthreads();

  int cur = 0;
  for (int kt = 0; kt < 32; ++kt) {
    if (kt < 31) {                          // prefetch kt+1 into buf^1
      const int kn = (kt + 1) * 64;
      unsigned short* Kd = Kls[cur ^ 1];
      unsigned short* Vd = Vls[cur ^ 1];
      async16(Kb + (size_t)(kn + srow) * 3072 + scol, Kd + tid * 8);
      async16(Kb + (size_t)(kn + 32 + srow) * 3072 + scol, Kd + 2048 + tid * 8);
      async16(Vb + (size_t)srow * SEQ + kn + scol, Vd + tid * 8);
      async16(Vb + (size_t)(32 + srow) * SEQ + kn + scol, Vd + 2048 + tid * 8);
    }
    const unsigned short* Kc = Kls[cur];
    const unsigned short* Vc = Vls[cur];

    short8 pa[2][4];   // [qg][ks] packed P fragments (PV A-operand)
#pragma unroll
    for (int kvg = 0; kvg < 2; ++kvg) {
      short8 kf[4];    // K A-frags: lane = kv-row kvg*32+l32, k = d-chunk
#pragma unroll
      for (int ds = 0; ds < 4; ++ds) {
        const int row = kvg * 32 + l32;
        kf[ds] = *(const short8*)(Kc + row * 64 + (((ds * 2 + hi) ^ (row & 7)) << 3));
      }
#pragma unroll
      for (int qg = 0; qg < 2; ++qg) {
        floatx16 s;
#pragma unroll
        for (int c = 0; c < 16; ++c) s[c] = 0.f;
#pragma unroll
        for (int ds = 0; ds < 4; ++ds) s = MFMA32(kf[ds], qf[qg][ds], s);
        float p[16];
#pragma unroll
        for (int c = 0; c < 16; ++c) p[c] = __builtin_amdgcn_exp2f(s[c]);
        rs[qg] += (((p[0] + p[1]) + (p[2] + p[3])) + ((p[4] + p[5]) + (p[6] + p[7])))
                + (((p[8] + p[9]) + (p[10] + p[11])) + ((p[12] + p[13]) + (p[14] + p[15])));
#pragma unroll
        for (int half = 0; half < 2; ++half) {   // ks = kvg*2 + half
          unsigned w0 = cvtpk(p[half * 8 + 0], p[half * 8 + 1]);
          unsigned w1 = cvtpk(p[half * 8 + 2], p[half * 8 + 3]);
          unsigned w2 = cvtpk(p[half * 8 + 4], p[half * 8 + 5]);
          unsigned w3 = cvtpk(p[half * 8 + 6], p[half * 8 + 7]);
          asm("v_permlane32_swap_b32 %0, %1" : "+v"(w0), "+v"(w2));
          asm("v_permlane32_swap_b32 %0, %1" : "+v"(w1), "+v"(w3));
          union { unsigned u[4]; short8 s8; } pk;
          pk.u[0] = w0; pk.u[1] = w1; pk.u[2] = w2; pk.u[3] = w3;
          pa[qg][kvg * 2 + half] = pk.s8;
        }
      }
    }

    // O += P V   (V B-frags: lane = d-col dg*32+l32, k = kv-chunk)
#pragma unroll
    for (int dg = 0; dg < 2; ++dg) {
      short8 vf[4];
#pragma unroll
      for (int ks = 0; ks < 4; ++ks) {
        const int row = dg * 32 + l32;
        vf[ks] = *(const short8*)(Vc + row * 64 + (((ks * 2 + hi) ^ (row & 7)) << 3));
      }
#pragma unroll
      for (int qg = 0; qg < 2; ++qg)
#pragma unroll
        for (int ks = 0; ks < 4; ++ks)
          o[qg][dg] = MFMA32(pa[qg][ks], vf[ks], o[qg][dg]);
    }

    // single barrier: drains the prefetch after compute hid its latency,
    // and protects buf[cur^1] before kt+1 overwrites it
    __syncthreads();
    cur ^= 1;
  }

  // lanes l and l+32 hold the same q; combine, publish per-q sums via LDS
  rs[0] += __shfl_xor(rs[0], 32);
  rs[1] += __shfl_xor(rs[1], 32);
  if (lane < 32) {
    rsls[w][l32] = rs[0];
    rsls[w][32 + l32] = rs[1];
  }
  // same-wave LDS readback; per-wave in-order, compiler inserts the lgkm wait

  // write ctx[b*SEQ + q][h*64 + d] bf16; O rows: q = (j&3)+8*(j>>2)+4*hi (+32qg)
#pragma unroll
  for (int qg = 0; qg < 2; ++qg)
#pragma unroll
    for (int j = 0; j < 16; ++j) {
      const int rl = (j & 3) + 8 * (j >> 2) + 4 * hi;
      const float inv = 1.f / rsls[w][qg * 32 + rl];
      const int gq = b * SEQ + qt * 256 + w * 64 + qg * 32 + rl;
      const size_t base = (size_t)gq * EMBED + h * 64;
#pragma unroll
      for (int dg = 0; dg < 2; ++dg)
        CTX[base + dg * 32 + l32] = f2bf(o[qg][dg][j] * inv);
    }
}

// ---------------- proj GEMM + bias + residual -> fp32 x ----------------
__global__ __launch_bounds__(256) void k_gemm_proj(const unsigned short* __restrict__ A,
                                                   const unsigned short* __restrict__ BT,
                                                   const float* __restrict__ bp,
                                                   const float* __restrict__ hid,
                                                   float* __restrict__ X) {
  __shared__ unsigned short Als[128 * 64];
  __shared__ unsigned short Bls[128 * 64];
  const int tid = threadIdx.x;
  const int m0 = blockIdx.x * 128, n0 = blockIdx.y * 128;
  const int w = tid >> 6, lane = tid & 63, l16 = lane & 15, quad = lane >> 4;
  const int l7 = l16 & 7;
  const int wrow = (w >> 1) * 64, wcol = (w & 1) * 64;

  floatx4 acc[4][4];
#pragma unroll
  for (int i = 0; i < 4; ++i)
#pragma unroll
    for (int j = 0; j < 4; ++j) acc[i][j] = {0.f, 0.f, 0.f, 0.f};

  const int srow = tid >> 3;
  const int scol = (((tid & 7) ^ (srow & 7)) * 8);
  const unsigned short* Ap = A + (size_t)(m0 + srow) * EMBED + scol;
  const unsigned short* Bp = BT + (size_t)(n0 + srow) * EMBED + scol;

  int ab[2], bb[2];
#pragma unroll
  for (int kc = 0; kc < 2; ++kc) {
    ab[kc] = (wrow + l16) * 64 + (((4 * kc + quad) ^ l7) << 3);
    bb[kc] = (wcol + l16) * 64 + (((4 * kc + quad) ^ l7) << 3);
  }

  for (int kt = 0; kt < 16; ++kt) {
    const int k0 = kt * 64;
#pragma unroll
    for (int i = 0; i < 4; ++i)
      async16(Ap + k0 + (size_t)i * 32 * EMBED, Als + i * 2048 + tid * 8);
#pragma unroll
    for (int i = 0; i < 4; ++i)
      async16(Bp + k0 + (size_t)i * 32 * EMBED, Bls + i * 2048 + tid * 8);
    __syncthreads();
    short8 af[4][2], bf[4][2];
#pragma unroll
    for (int mt = 0; mt < 4; ++mt)
#pragma unroll
      for (int kc = 0; kc < 2; ++kc)
        af[mt][kc] = *(const short8*)(Als + ab[kc] + mt * 1024);
#pragma unroll
    for (int nt = 0; nt < 4; ++nt)
#pragma unroll
      for (int kc = 0; kc < 2; ++kc)
        bf[nt][kc] = *(const short8*)(Bls + bb[kc] + nt * 1024);
#pragma unroll
    for (int kc = 0; kc < 2; ++kc)
#pragma unroll
      for (int mt = 0; mt < 4; ++mt)
#pragma unroll
        for (int nt = 0; nt < 4; ++nt)
          acc[mt][nt] = MFMA16(af[mt][kc], bf[nt][kc], acc[mt][nt]);
    __syncthreads();
  }

  float bias[4];
#pragma unroll
  for (int nt = 0; nt < 4; ++nt) bias[nt] = bp[n0 + wcol + nt * 16 + l16];
#pragma unroll
  for (int mt = 0; mt < 4; ++mt)
#pragma unroll
    for (int r = 0; r < 4; ++r) {
      int gm = m0 + wrow + mt * 16 + quad * 4 + r;
      size_t base = (size_t)gm * EMBED + n0 + wcol;
#pragma unroll
      for (int nt = 0; nt < 4; ++nt) {
        size_t idx = base + nt * 16 + l16;
        X[idx] = acc[mt][nt][r] + bias[nt] + hid[idx];
      }
    }
}

// ---------------- in-place LayerNorm over E=1024, one block per row ----------------
__global__ __launch_bounds__(256) void k_ln(float* __restrict__ x,
                                            const float* __restrict__ gamma,
                                            const float* __restrict__ beta) {
  int row = blockIdx.x, tid = threadIdx.x;
  float4* rp = (float4*)(x + (size_t)row * EMBED);
  float4 v = rp[tid];
  float s = v.x + v.y + v.z + v.w;
  float q = v.x * v.x + v.y * v.y + v.z * v.z + v.w * v.w;
#pragma unroll
  for (int off = 1; off < 64; off <<= 1) {
    s += __shfl_xor(s, off);
    q += __shfl_xor(q, off);
  }
  __shared__ float ss[4], sq[4];
  int w = tid >> 6;
  if ((tid & 63) == 0) { ss[w] = s; sq[w] = q; }
  __syncthreads();
  s = ss[0] + ss[1] + ss[2] + ss[3];
  q = sq[0] + sq[1] + sq[2] + sq[3];
  float mean = s * (1.f / 1024.f);
  float var = q * (1.f / 1024.f) - mean * mean;
  float rstd = rsqrtf(var + 1e-8f);
  float4 g = ((const float4*)gamma)[tid];
  float4 be = ((const float4*)beta)[tid];
  v.x = (v.x - mean) * rstd * g.x + be.x;
  v.y = (v.y - mean) * rstd * g.y + be.y;
  v.z = (v.z - mean) * rstd * g.z + be.z;
  v.w = (v.w - mean) * rstd * g.w + be.w;
  rp[tid] = v;
}

extern "C" void kernel_launch(void* const* d_in, const int* in_sizes, int n_in,
                              void* d_out, int out_size, void* d_ws, size_t ws_size,
                              hipStream_t stream) {
  const float* hid   = (const float*)d_in[0];
  const float* Wq    = (const float*)d_in[1];
  const float* bq    = (const float*)d_in[2];
  const float* Wk    = (const float*)d_in[3];
  const float* bk    = (const float*)d_in[4];
  const float* Wv    = (const float*)d_in[5];
  const float* bv    = (const float*)d_in[6];
  const float* Wp    = (const float*)d_in[7];
  const float* bp    = (const float*)d_in[8];
  const float* gamma = (const float*)d_in[9];
  const float* beta  = (const float*)d_in[10];
  float* out = (float*)d_out;

  char* ws = (char*)d_ws;
  unsigned short* hidA = (unsigned short*)ws;                          // 16 MB  [8192][1024]
  unsigned short* WT   = (unsigned short*)(ws + (size_t)(16 << 20));   //  8 MB  [4096][1024]
  unsigned short* QKV  = (unsigned short*)(ws + (size_t)(24 << 20));   // 48 MB  [8192][3072] (V third unused)
  unsigned short* VT   = (unsigned short*)(ws + (size_t)(72 << 20));   // 16 MB  [64][64][2048]
  unsigned short* CTX  = (unsigned short*)(ws + (size_t)(88 << 20));   // 16 MB  [8192][1024]

  k_prep<<<5120, 256, 0, stream>>>(hid, hidA, Wq, Wk, Wv, Wp, WT);
  k_gemm_qkv<<<dim3(64, 24), 256, 0, stream>>>(hidA, WT, bq, bk, bv, QKV, VT);
  k_attn<<<dim3(64, 8), 256, 0, stream>>>(QKV, VT, CTX);
  k_gemm_proj<<<dim3(64, 8), 256, 0, stream>>>(CTX, WT + (size_t)3 * EMBED * EMBED, bp, hid, out);
  k_ln<<<8192, 256, 0, stream>>>(out, gamma, beta);
}